// Round 6
// baseline (1864.577 us; speedup 1.0000x reference)
//
#include <hip/hip_runtime.h>
#include <hip/hip_bf16.h>
#include <hip/hip_cooperative_groups.h>

namespace cg = cooperative_groups;

#define DEPTH_T 11
#define HDIM 1024
#define VDIM 32001
#define NNODES 4095   // 2^12 - 1
#define LDV 32008     // padded bf16 logit row stride (x2B = 64016, 16B-aligned)

typedef __attribute__((ext_vector_type(8))) short bf16x8;
typedef __attribute__((ext_vector_type(8))) unsigned short ushort8;
typedef __attribute__((ext_vector_type(4))) float floatx4;

// Pre-order position of BFS/heap node m (0-based), perfect binary tree depth DEPTH_T.
__device__ __forceinline__ int preorder_pos(int m) {
    int q = m + 1;
    int d = 31 - __clz(q);
    int pos = 0;
    for (int i = 1; i <= d; ++i) {
        int b = (q >> (d - i)) & 1;
        pos += 1 + b * ((1 << (DEPTH_T - i + 1)) - 1);
    }
    return pos;
}

__device__ __forceinline__ float bf2f(unsigned short u) {
    return __uint_as_float(((unsigned)u) << 16);
}

#define BM 128
#define BN 128
#define BK 32

// C = A [M,K] @ Bt^T (Bt is [N,K] bf16 row-major) + bias[N]
// MODE 0: bf16 out = sigmoid(acc+bias)        MODE 1: bf16 out = acc+bias
// MODE 2: f32 out, rows scattered by preorder  MODE 3: bf16 out, rows scattered
template<int MODE, bool SWAPG>
__global__ __launch_bounds__(256, 2) void gemm_bt(
    const __hip_bfloat16* __restrict__ A,
    const __hip_bfloat16* __restrict__ Bt,
    const float* __restrict__ bias,
    void* __restrict__ outp,
    int M, int N, int K, int ldout)
{
    __shared__ __align__(16) __hip_bfloat16 As[BM][BK];
    __shared__ __align__(16) __hip_bfloat16 Bs[BN][BK];

    const int tid  = threadIdx.x;
    const int wave = tid >> 6;
    const int lane = tid & 63;
    const int m0 = (SWAPG ? blockIdx.x : blockIdx.y) * BM;
    const int n0 = (SWAPG ? blockIdx.y : blockIdx.x) * BN;
    const int wm = (wave & 1) * 64;
    const int wn = (wave >> 1) * 64;

    floatx4 acc[4][4];
#pragma unroll
    for (int i = 0; i < 4; ++i)
#pragma unroll
        for (int j = 0; j < 4; ++j) acc[i][j] = (floatx4)0.0f;

    const int lrow = lane >> 2;
    const int lcol = (lane & 3) * 8;
    const int fr = lane & 15;
    const int fk = (lane >> 4) * 8;

    for (int k0 = 0; k0 < K; k0 += BK) {
        __syncthreads();
#pragma unroll
        for (int t = 0; t < 2; ++t) {
            const int r = (wave * 2 + t) * 16;
            int gm = m0 + r + lrow; gm = gm < M ? gm : M - 1;
            const __hip_bfloat16* gp = A + (size_t)gm * K + (k0 + lcol);
            __builtin_amdgcn_global_load_lds(
                (const __attribute__((address_space(1))) void*)gp,
                (__attribute__((address_space(3))) void*)(&As[r][0]),
                16, 0, 0);
        }
#pragma unroll
        for (int t = 0; t < 2; ++t) {
            const int r = (wave * 2 + t) * 16;
            int gn = n0 + r + lrow; gn = gn < N ? gn : N - 1;
            const __hip_bfloat16* gp = Bt + (size_t)gn * K + (k0 + lcol);
            __builtin_amdgcn_global_load_lds(
                (const __attribute__((address_space(1))) void*)gp,
                (__attribute__((address_space(3))) void*)(&Bs[r][0]),
                16, 0, 0);
        }
        __syncthreads();

        bf16x8 af[4], bfv[4];
#pragma unroll
        for (int i = 0; i < 4; ++i)
            af[i] = *(const bf16x8*)(&As[wm + i * 16 + fr][fk]);
#pragma unroll
        for (int j = 0; j < 4; ++j)
            bfv[j] = *(const bf16x8*)(&Bs[wn + j * 16 + fr][fk]);
#pragma unroll
        for (int i = 0; i < 4; ++i)
#pragma unroll
            for (int j = 0; j < 4; ++j)
                acc[i][j] = __builtin_amdgcn_mfma_f32_16x16x32_bf16(
                    af[i], bfv[j], acc[i][j], 0, 0, 0);
    }

    const int rq = (lane >> 4) * 4;
    if (MODE >= 2) {
#pragma unroll
        for (int i = 0; i < 4; ++i) {
#pragma unroll
            for (int r = 0; r < 4; ++r) {
                const int gm = m0 + wm + i * 16 + rq + r;
                if (gm >= M) continue;
                const size_t orow = (size_t)preorder_pos(gm) * ldout;
#pragma unroll
                for (int j = 0; j < 4; ++j) {
                    const int gn = n0 + wn + j * 16 + fr;
                    if (gn < N) {
                        float v = acc[i][j][r] + bias[gn];
                        if (MODE == 2) ((float*)outp)[orow + gn] = v;
                        else ((__hip_bfloat16*)outp)[orow + gn] = __float2bfloat16(v);
                    }
                }
            }
        }
    } else {
        __hip_bfloat16* O = (__hip_bfloat16*)outp;
#pragma unroll
        for (int i = 0; i < 4; ++i) {
#pragma unroll
            for (int r = 0; r < 4; ++r) {
                const int gm = m0 + wm + i * 16 + rq + r;
                if (gm >= M) continue;
#pragma unroll
                for (int j = 0; j < 4; ++j) {
                    const int gn = n0 + wn + j * 16 + fr;
                    if (gn < N) {
                        float v = acc[i][j][r] + bias[gn];
                        if (MODE == 0) v = 1.0f / (1.0f + __expf(-v));
                        O[(size_t)gm * ldout + gn] = __float2bfloat16(v);
                    }
                }
            }
        }
    }
}

// ============================================================================
// 256x256 8-phase GEMM — RESTORED to the R1 configuration (best measured:
// 684 us, FETCH 595 MB, MfmaUtil 34%). Schedule experiments (counted lgkm,
// read-ahead, XCD mappings) were all neutral-to-negative; plain 2D grid
// (x = m-tiles fastest: 16 consecutive blocks share one 1-MB B strip).
// ============================================================================
#define B2M 256
#define B2N 256

template<int MODE>
__global__ __launch_bounds__(512, 2) void gemm256(
    const __hip_bfloat16* __restrict__ A,
    const __hip_bfloat16* __restrict__ Bt,
    const float* __restrict__ bias,
    void* __restrict__ outp,
    int M, int N, int K, int ldout)
{
    __shared__ __align__(16) char smem[131072];

    const int tid  = threadIdx.x;
    const int wave = tid >> 6;
    const int lane = tid & 63;
    const int m0 = blockIdx.x * B2M;
    const int n0 = blockIdx.y * B2N;
    const int wm = (wave >> 2) * 128;   // 0 / 128
    const int wn = (wave & 3) * 64;     // 0 / 64 / 128 / 192
    const int nkt = K >> 6;             // # 64-wide K-tiles (even)

    // staging: per-lane pre-swizzled global source
    const int s_row = lane >> 3;                    // 0..7
    const int s_col = ((lane & 7) ^ s_row) * 8;     // bf16 col within 64-col slab

    // fragment read addressing (swizzled)
    const int fr  = lane & 15;
    const int fkq = lane >> 4;                      // 0..3
    const int swz = (fr & 7) << 4;
    const int c0  = (fkq * 16) ^ swz;               // ks=0 col-bytes
    const int c1  = (64 + fkq * 16) ^ swz;          // ks=1 col-bytes
    const int aoff = (wm + fr) * 128;
    const int boff = 32768 + (wn + fr) * 128;

    floatx4 acc[8][4];
#pragma unroll
    for (int i = 0; i < 8; ++i)
#pragma unroll
        for (int j = 0; j < 4; ++j) acc[i][j] = (floatx4)0.0f;

    bf16x8 a0[8], a1[8], b0[4], b1[4];

    auto stage = [&](int bsel, int mat, int h, int kt) {
        const int ktc = kt < nkt ? kt : 0;
        const __hip_bfloat16* gb = mat ? Bt : A;
        const int lim = mat ? N : M;
        const int g0  = mat ? n0 : m0;
#pragma unroll
        for (int inst = 0; inst < 2; ++inst) {
            const int rg = inst * 8 + wave;
            int gr = g0 + h * 128 + rg * 8 + s_row;
            gr = gr < lim ? gr : lim - 1;
            const __hip_bfloat16* gp = gb + (size_t)gr * K + (ktc * 64 + s_col);
            __builtin_amdgcn_global_load_lds(
                (const __attribute__((address_space(1))) void*)gp,
                (__attribute__((address_space(3))) void*)
                    (smem + bsel * 65536 + mat * 32768 + h * 16384 + rg * 1024),
                16, 0, 0);
        }
    };

#define RD_A(dst, bsel, cc) \
    _Pragma("unroll") \
    for (int i = 0; i < 8; ++i) \
        dst[i] = *(const bf16x8*)(smem + (bsel) * 65536 + aoff + i * 2048 + (cc));
#define RD_B(dst, bsel, cc) \
    _Pragma("unroll") \
    for (int j = 0; j < 4; ++j) \
        dst[j] = *(const bf16x8*)(smem + (bsel) * 65536 + boff + j * 2048 + (cc));
#define MM(ib, AA, BB) \
    _Pragma("unroll") \
    for (int i = 0; i < 4; ++i) \
    _Pragma("unroll") \
    for (int j = 0; j < 4; ++j) \
        acc[(ib) + i][j] = __builtin_amdgcn_mfma_f32_16x16x32_bf16( \
            AA[(ib) + i], BB[j], acc[(ib) + i][j], 0, 0, 0);
#define LGKM0  asm volatile("s_waitcnt lgkmcnt(0)" ::: "memory")
#define VM4    asm volatile("s_waitcnt vmcnt(4)" ::: "memory")
#define BAR    __builtin_amdgcn_s_barrier()
#define PRIO1  __builtin_amdgcn_s_setprio(1)
#define PRIO0  __builtin_amdgcn_s_setprio(0)

    // ---- prologue: t0 fully -> buf0; t1 A-halves -> buf1 (stay in flight x2) ----
    stage(0, 0, 0, 0);  // buf0 A-lo  (t0)
    stage(0, 0, 1, 0);  // buf0 A-hi
    stage(0, 1, 0, 0);  // buf0 B-lo
    stage(0, 1, 1, 0);  // buf0 B-hi
    stage(1, 0, 0, 1);  // buf1 A-lo  (t1)
    stage(1, 0, 1, 1);  // buf1 A-hi
    VM4;                // t0's 4 units landed; t1's 2 A-units in flight
    BAR;

#pragma unroll 1
    for (int t = 0; t < nkt; t += 2) {
        // P1
        RD_A(a0, 0, c0); RD_B(b0, 0, c0);
        stage(1, 1, 0, t + 1);              // buf1 B-lo (t+1)
        BAR; LGKM0;
        PRIO1; MM(0, a0, b0); PRIO0;
        BAR;
        // P2
        RD_A(a1, 0, c1); RD_B(b1, 0, c1);
        stage(1, 1, 1, t + 1);              // buf1 B-hi (t+1)
        BAR; LGKM0;
        PRIO1; MM(4, a0, b0); PRIO0;
        BAR;
        // P3 (buf0 reads all complete -> restage A region)
        stage(0, 0, 0, t + 2);              // buf0 A-lo (t+2)
        BAR;
        PRIO1; MM(0, a1, b1); PRIO0;
        BAR;
        // P4
        stage(0, 0, 1, t + 2);              // buf0 A-hi (t+2)
        VM4;                                // t+1 fully landed
        BAR;
        PRIO1; MM(4, a1, b1); PRIO0;
        BAR;
        // P5
        RD_A(a0, 1, c0); RD_B(b0, 1, c0);
        stage(0, 1, 0, t + 2);              // buf0 B-lo (t+2)
        BAR; LGKM0;
        PRIO1; MM(0, a0, b0); PRIO0;
        BAR;
        // P6
        RD_A(a1, 1, c1); RD_B(b1, 1, c1);
        stage(0, 1, 1, t + 2);              // buf0 B-hi (t+2)
        BAR; LGKM0;
        PRIO1; MM(4, a0, b0); PRIO0;
        BAR;
        // P7 (buf1 reads all complete -> restage A region)
        stage(1, 0, 0, t + 3);              // buf1 A-lo (t+3)
        BAR;
        PRIO1; MM(0, a1, b1); PRIO0;
        BAR;
        // P8
        stage(1, 0, 1, t + 3);              // buf1 A-hi (t+3)
        VM4;                                // t+2 fully landed
        BAR;
        PRIO1; MM(4, a1, b1); PRIO0;
        BAR;
    }

#undef RD_A
#undef RD_B
#undef MM
#undef LGKM0
#undef VM4
#undef BAR
#undef PRIO1
#undef PRIO0

    // ---- epilogue: C/D layout col = lane&15, row = (lane>>4)*4 + reg ----
    const int rq = (lane >> 4) * 4;
    if (MODE >= 2) {
#pragma unroll
        for (int i = 0; i < 8; ++i) {
#pragma unroll
            for (int r = 0; r < 4; ++r) {
                const int gm = m0 + wm + i * 16 + rq + r;
                if (gm >= M) continue;
                const size_t orow = (size_t)preorder_pos(gm) * ldout;
#pragma unroll
                for (int j = 0; j < 4; ++j) {
                    const int gn = n0 + wn + j * 16 + fr;
                    if (gn < N) {
                        float v = acc[i][j][r] + bias[gn];
                        if (MODE == 2) ((float*)outp)[orow + gn] = v;
                        else ((__hip_bfloat16*)outp)[orow + gn] = __float2bfloat16(v);
                    }
                }
            }
        }
    } else {
        __hip_bfloat16* O = (__hip_bfloat16*)outp;
#pragma unroll
        for (int i = 0; i < 8; ++i) {
#pragma unroll
            for (int r = 0; r < 4; ++r) {
                const int gm = m0 + wm + i * 16 + rq + r;
                if (gm >= M) continue;
#pragma unroll
                for (int j = 0; j < 4; ++j) {
                    const int gn = n0 + wn + j * 16 + fr;
                    if (gn < N) {
                        float v = acc[i][j][r] + bias[gn];
                        if (MODE == 0) v = 1.0f / (1.0f + __expf(-v));
                        O[(size_t)gm * ldout + gn] = __float2bfloat16(v);
                    }
                }
            }
        }
    }
}

// Small-M GEMM: no LDS, no barriers — loads software-pipeline via vmcnt.
template<int MODE>
__global__ __launch_bounds__(256) void gemm_small(
    const __hip_bfloat16* __restrict__ A,
    const __hip_bfloat16* __restrict__ Bt,
    const float* __restrict__ bias,
    __hip_bfloat16* __restrict__ O,
    int M, int N, int K)
{
    const int wave = threadIdx.x >> 6, lane = threadIdx.x & 63;
    const int n0 = blockIdx.x * 64 + wave * 16;
    const int m0 = blockIdx.y * 16;
    const int fr = lane & 15, fk = (lane >> 4) * 8;

    int am = m0 + fr; am = am < M ? am : M - 1;
    const __hip_bfloat16* ap = A + (size_t)am * K + fk;
    const __hip_bfloat16* bp = Bt + (size_t)(n0 + fr) * K + fk;

    floatx4 acc = (floatx4)0.0f;
#pragma unroll 8
    for (int k0 = 0; k0 < K; k0 += 32) {
        bf16x8 av = *(const bf16x8*)(ap + k0);
        bf16x8 bv = *(const bf16x8*)(bp + k0);
        acc = __builtin_amdgcn_mfma_f32_16x16x32_bf16(av, bv, acc, 0, 0, 0);
    }

    const int rq = (lane >> 4) * 4;
    const int gn = n0 + fr;
    const float b = bias[gn];
#pragma unroll
    for (int r = 0; r < 4; ++r) {
        const int gm = m0 + rq + r;
        if (gm >= M) continue;
        float v = acc[r] + b;
        if (MODE == 0) v = 1.0f / (1.0f + __expf(-v));
        O[(size_t)gm * N + gn] = __float2bfloat16(v);
    }
}

// ============================================================================
// Cooperative fused child phase, levels 0..8 (Md = 1..256). Replaces 18 tiny
// launches (launch+drain latency dominated) with ONE kernel + 18 grid.sync().
// Per level: T = sigmoid(Hd @ W1cT^T + b1c)  [Md,2048]  (K=1024)
//            Hn = T @ W2cT^T + b2c           [Md,2048]  (K=2048)
// Wave-tiled exactly like gemm_small (16x16 MFMA tiles, bf16x8 loads, clamp
// on A rows); waves grab tiles round-robin; grid.sync() between dependent
// stages. 256 blocks x 256 thr -> 1 block/CU, trivially co-resident.
// ============================================================================
__global__ __launch_bounds__(256) void child_small_levels(
    const __hip_bfloat16* __restrict__ W1cT, const float* __restrict__ b1c,
    const __hip_bfloat16* __restrict__ W2cT, const float* __restrict__ b2c,
    __hip_bfloat16* __restrict__ Hall, __hip_bfloat16* __restrict__ Tt)
{
    cg::grid_group grid = cg::this_grid();
    const int wave = threadIdx.x >> 6, lane = threadIdx.x & 63;
    const int gw = blockIdx.x * 4 + wave;          // 0..1023 global wave id
    const int fr = lane & 15, fk = (lane >> 4) * 8;
    const int rq = (lane >> 4) * 4;

    for (int d = 0; d <= 8; ++d) {
        const int Md = 1 << d;
        const __hip_bfloat16* Hd = Hall + (size_t)(Md - 1) * HDIM;
        __hip_bfloat16* Hn = Hall + (size_t)((2 << d) - 1) * HDIM;
        const int mt = (Md + 15) >> 4;             // row-tiles
        const int ntiles = mt * 128;               // 2048/16 col-tiles

        // ---- GEMM1: Tt = sigmoid(Hd @ W1cT^T + b1c), K=1024 ----
        for (int tile = gw; tile < ntiles; tile += 1024) {
            const int m0 = (tile >> 7) * 16;
            const int n0 = (tile & 127) * 16;
            int am = m0 + fr; am = am < Md ? am : Md - 1;
            const __hip_bfloat16* ap = Hd + (size_t)am * 1024 + fk;
            const __hip_bfloat16* bp = W1cT + (size_t)(n0 + fr) * 1024 + fk;
            floatx4 acc = (floatx4)0.0f;
#pragma unroll 8
            for (int k0 = 0; k0 < 1024; k0 += 32) {
                bf16x8 av = *(const bf16x8*)(ap + k0);
                bf16x8 bv = *(const bf16x8*)(bp + k0);
                acc = __builtin_amdgcn_mfma_f32_16x16x32_bf16(av, bv, acc, 0, 0, 0);
            }
            const int gn = n0 + fr;
            const float b = b1c[gn];
#pragma unroll
            for (int r = 0; r < 4; ++r) {
                const int gm = m0 + rq + r;
                if (gm >= Md) continue;
                float v = 1.0f / (1.0f + __expf(-(acc[r] + b)));
                Tt[(size_t)gm * 2048 + gn] = __float2bfloat16(v);
            }
        }
        grid.sync();

        // ---- GEMM2: Hn = Tt @ W2cT^T + b2c, K=2048 ----
        for (int tile = gw; tile < ntiles; tile += 1024) {
            const int m0 = (tile >> 7) * 16;
            const int n0 = (tile & 127) * 16;
            int am = m0 + fr; am = am < Md ? am : Md - 1;
            const __hip_bfloat16* ap = Tt + (size_t)am * 2048 + fk;
            const __hip_bfloat16* bp = W2cT + (size_t)(n0 + fr) * 2048 + fk;
            floatx4 acc = (floatx4)0.0f;
#pragma unroll 8
            for (int k0 = 0; k0 < 2048; k0 += 32) {
                bf16x8 av = *(const bf16x8*)(ap + k0);
                bf16x8 bv = *(const bf16x8*)(bp + k0);
                acc = __builtin_amdgcn_mfma_f32_16x16x32_bf16(av, bv, acc, 0, 0, 0);
            }
            const int gn = n0 + fr;
            const float b = b2c[gn];
#pragma unroll
            for (int r = 0; r < 4; ++r) {
                const int gm = m0 + rq + r;
                if (gm >= Md) continue;
                Hn[(size_t)gm * 2048 + gn] = __float2bfloat16(acc[r] + b);
            }
        }
        grid.sync();
    }
}

// in [R,C] f32 row-major -> outT [C,R] bf16 row-major. 64x64 tiles.
__global__ __launch_bounds__(256) void transpose_to_bf16(
    const float* __restrict__ in, __hip_bfloat16* __restrict__ outT, int R, int C)
{
    __shared__ float tile[64][65];
    const int c0 = blockIdx.x * 64, r0 = blockIdx.y * 64;
    const int tx = threadIdx.x & 63, ty = threadIdx.x >> 6;
#pragma unroll
    for (int i = 0; i < 64; i += 4) {
        int r = r0 + ty + i, c = c0 + tx;
        tile[ty + i][tx] = (r < R && c < C) ? in[(size_t)r * C + c] : 0.0f;
    }
    __syncthreads();
#pragma unroll
    for (int i = 0; i < 64; i += 4) {
        int rr = c0 + ty + i, cc = r0 + tx;
        if (rr < C && cc < R) outT[(size_t)rr * R + cc] = __float2bfloat16(tile[tx][ty + i]);
    }
}

__global__ __launch_bounds__(256) void convert_root(
    const float* __restrict__ in, __hip_bfloat16* __restrict__ out)
{
    int i = blockIdx.x * 256 + threadIdx.x;
    if (i < HDIM) out[i] = __float2bfloat16(in[i]);
}

// Log-softmax over bf16 logit rows (stride LDV), writing fp32 rows (stride VDIM).
__global__ __launch_bounds__(256) void logsoftmax_bf16(
    const unsigned short* __restrict__ L, float* __restrict__ O)
{
    extern __shared__ char smem[];
    unsigned short* rb = (unsigned short*)smem;
    float* wred = (float*)(smem + 64016);
    const int tid = threadIdx.x, lane = tid & 63, wv = tid >> 6;
    const unsigned short* src = L + (size_t)blockIdx.x * LDV;

    float m = -3.0e38f;
    for (int j = tid * 8; j < 32000; j += 2048) {
        ushort8 u = *(const ushort8*)(src + j);
        *(ushort8*)(rb + j) = u;
#pragma unroll
        for (int t = 0; t < 8; ++t) m = fmaxf(m, bf2f(u[t]));
    }
    if (tid == 0) { unsigned short u = src[32000]; rb[32000] = u; m = fmaxf(m, bf2f(u)); }
#pragma unroll
    for (int off = 32; off; off >>= 1) m = fmaxf(m, __shfl_xor(m, off, 64));
    if (lane == 0) wred[wv] = m;
    __syncthreads();
    const float M4 = fmaxf(fmaxf(wred[0], wred[1]), fmaxf(wred[2], wred[3]));

    float s = 0.0f;
    for (int j = tid * 8; j < 32000; j += 2048) {
        ushort8 u = *(const ushort8*)(rb + j);
#pragma unroll
        for (int t = 0; t < 8; ++t) s += __expf(bf2f(u[t]) - M4);
    }
    if (tid == 0) s += __expf(bf2f(rb[32000]) - M4);
#pragma unroll
    for (int off = 32; off; off >>= 1) s += __shfl_xor(s, off, 64);
    if (lane == 0) wred[4 + wv] = s;
    __syncthreads();
    const float lse = M4 + __logf(wred[4] + wred[5] + wred[6] + wred[7]);

    float* dst = O + (size_t)blockIdx.x * VDIM;
    for (int j = tid * 8; j < 32000; j += 2048) {
        ushort8 u = *(const ushort8*)(rb + j);
#pragma unroll
        for (int t = 0; t < 8; ++t) dst[j + t] = bf2f(u[t]) - lse;
    }
    if (tid == 0) dst[32000] = bf2f(rb[32000]) - lse;
}

// Fallback: in-place fp32 log_softmax (used only if ws too small for bf16 logits).
__global__ __launch_bounds__(256) void logsoftmax_rows(float* __restrict__ O, int n)
{
    __shared__ float sm[256], ssum[256];
    const int tid = threadIdx.x;
    float* p = O + (size_t)blockIdx.x * n;
    float m = -3.0e38f, s = 0.0f;
    for (int j = tid; j < n; j += 256) {
        float x = p[j];
        float nm = fmaxf(m, x);
        s = s * __expf(m - nm) + __expf(x - nm);
        m = nm;
    }
    sm[tid] = m; ssum[tid] = s;
    __syncthreads();
    for (int off = 128; off > 0; off >>= 1) {
        if (tid < off) {
            float m2 = sm[tid + off], s2 = ssum[tid + off];
            float nm = fmaxf(sm[tid], m2);
            ssum[tid] = ssum[tid] * __expf(sm[tid] - nm) + s2 * __expf(m2 - nm);
            sm[tid] = nm;
        }
        __syncthreads();
    }
    const float lse = sm[0] + __logf(ssum[0]);
    for (int j = tid; j < n; j += 256) p[j] -= lse;
}

extern "C" void kernel_launch(void* const* d_in, const int* in_sizes, int n_in,
                              void* d_out, int out_size, void* d_ws, size_t ws_size,
                              hipStream_t stream)
{
    const float* root = (const float*)d_in[0];
    const float* W1v  = (const float*)d_in[1];   // [1024, 2048]
    const float* b1v  = (const float*)d_in[2];
    const float* W2v  = (const float*)d_in[3];   // [2048, 32001]
    const float* b2v  = (const float*)d_in[4];
    const float* W1c  = (const float*)d_in[5];   // [1024, 2048]
    const float* b1c  = (const float*)d_in[6];
    const float* W2c  = (const float*)d_in[7];   // [2048, 2048]
    const float* b2c  = (const float*)d_in[8];

    char* ws = (char*)d_ws;
    __hip_bfloat16* Hall = (__hip_bfloat16*)(ws + 0);             // 4095x1024 (8 MB rgn)
    __hip_bfloat16* X1   = (__hip_bfloat16*)(ws +   8388608ull);  // 4095x2048 (16 MB rgn)
    __hip_bfloat16* Tt   = (__hip_bfloat16*)(ws +  25165824ull);  // 1024x2048 (4 MB)
    __hip_bfloat16* W1vT = (__hip_bfloat16*)(ws +  29360128ull);  // 2048x1024 (4 MB)
    __hip_bfloat16* W1cT = (__hip_bfloat16*)(ws +  33554432ull);  // 2048x1024 (4 MB)
    __hip_bfloat16* W2cT = (__hip_bfloat16*)(ws +  37748736ull);  // 2048x2048 (8 MB)
    __hip_bfloat16* W2vT = (__hip_bfloat16*)(ws +  46137344ull);  // 32001x2048 (ends 177,213,440)
    __hip_bfloat16* Lb   = (__hip_bfloat16*)(ws + 177213440ull);  // 4095xLDV bf16 logits
    const bool bf16_logits = ws_size >= 177213440ull + (size_t)NNODES * LDV * 2;

    dim3 blk(256);

    transpose_to_bf16<<<dim3( 32, 16), blk, 0, stream>>>(W1v, W1vT, 1024, 2048);
    transpose_to_bf16<<<dim3(501, 32), blk, 0, stream>>>(W2v, W2vT, 2048, VDIM);
    transpose_to_bf16<<<dim3( 32, 16), blk, 0, stream>>>(W1c, W1cT, 1024, 2048);
    transpose_to_bf16<<<dim3( 32, 32), blk, 0, stream>>>(W2c, W2cT, 2048, 2048);
    convert_root<<<dim3(4), blk, 0, stream>>>(root, Hall);

    // Child phase levels 0..8 fused into one cooperative kernel (18 grid syncs
    // replace 18 kernel launches). Levels 9..10 use the tiled gemm_bt path.
    {
        void* args[] = { (void*)&W1cT, (void*)&b1c, (void*)&W2cT, (void*)&b2c,
                         (void*)&Hall, (void*)&Tt };
        hipLaunchCooperativeKernel((const void*)child_small_levels,
                                   dim3(256), dim3(256), args, 0, stream);
    }
    for (int d = 9; d < DEPTH_T; ++d) {
        const int Md = 1 << d;
        __hip_bfloat16* Hd = Hall + (size_t)(Md - 1) * HDIM;
        __hip_bfloat16* Hn = Hall + (size_t)((2 << d) - 1) * HDIM;
        dim3 g(16, Md / 128);
        gemm_bt<0, false><<<g, blk, 0, stream>>>(Hd, W1cT, b1c, Tt, Md, 2048, 1024, 2048);
        gemm_bt<1, false><<<g, blk, 0, stream>>>(Tt, W2cT, b2c, Hn, Md, 2048, 2048, 2048);
    }

    // Value phase.
    gemm_bt<0, false><<<dim3(16, 32), blk, 0, stream>>>(Hall, W1vT, b1v, X1, NNODES, 2048, 1024, 2048);
    if (bf16_logits) {
        gemm256<3><<<dim3(16, 126), dim3(512), 0, stream>>>(X1, W2vT, b2v, Lb, NNODES, VDIM, 2048, LDV);
        logsoftmax_bf16<<<dim3(NNODES), blk, 64048, stream>>>((const unsigned short*)Lb, (float*)d_out);
    } else {
        gemm_bt<2, true><<<dim3(32, 251), blk, 0, stream>>>(X1, W2vT, b2v, d_out, NNODES, VDIM, 2048, VDIM);
        logsoftmax_rows<<<dim3(NNODES), blk, 0, stream>>>((float*)d_out, VDIM);
    }
}

// Round 7
// 1453.230 us; speedup vs baseline: 1.2831x; 1.2831x over previous
//
#include <hip/hip_runtime.h>
#include <hip/hip_bf16.h>

#define DEPTH_T 11
#define HDIM 1024
#define VDIM 32001
#define NNODES 4095   // 2^12 - 1
#define LDV 32008     // padded bf16 logit row stride (x2B = 64016, 16B-aligned)

typedef __attribute__((ext_vector_type(8))) short bf16x8;
typedef __attribute__((ext_vector_type(8))) unsigned short ushort8;
typedef __attribute__((ext_vector_type(4))) float floatx4;

// Pre-order position of BFS/heap node m (0-based), perfect binary tree depth DEPTH_T.
__device__ __forceinline__ int preorder_pos(int m) {
    int q = m + 1;
    int d = 31 - __clz(q);
    int pos = 0;
    for (int i = 1; i <= d; ++i) {
        int b = (q >> (d - i)) & 1;
        pos += 1 + b * ((1 << (DEPTH_T - i + 1)) - 1);
    }
    return pos;
}

__device__ __forceinline__ float bf2f(unsigned short u) {
    return __uint_as_float(((unsigned)u) << 16);
}

#define BM 128
#define BN 128
#define BK 32

// C = A [M,K] @ Bt^T (Bt is [N,K] bf16 row-major) + bias[N]
// MODE 0: bf16 out = sigmoid(acc+bias)        MODE 1: bf16 out = acc+bias
// MODE 2: f32 out, rows scattered by preorder  MODE 3: bf16 out, rows scattered
template<int MODE, bool SWAPG>
__global__ __launch_bounds__(256, 2) void gemm_bt(
    const __hip_bfloat16* __restrict__ A,
    const __hip_bfloat16* __restrict__ Bt,
    const float* __restrict__ bias,
    void* __restrict__ outp,
    int M, int N, int K, int ldout)
{
    __shared__ __align__(16) __hip_bfloat16 As[BM][BK];
    __shared__ __align__(16) __hip_bfloat16 Bs[BN][BK];

    const int tid  = threadIdx.x;
    const int wave = tid >> 6;
    const int lane = tid & 63;
    const int m0 = (SWAPG ? blockIdx.x : blockIdx.y) * BM;
    const int n0 = (SWAPG ? blockIdx.y : blockIdx.x) * BN;
    const int wm = (wave & 1) * 64;
    const int wn = (wave >> 1) * 64;

    floatx4 acc[4][4];
#pragma unroll
    for (int i = 0; i < 4; ++i)
#pragma unroll
        for (int j = 0; j < 4; ++j) acc[i][j] = (floatx4)0.0f;

    const int lrow = lane >> 2;
    const int lcol = (lane & 3) * 8;
    const int fr = lane & 15;
    const int fk = (lane >> 4) * 8;

    for (int k0 = 0; k0 < K; k0 += BK) {
        __syncthreads();
#pragma unroll
        for (int t = 0; t < 2; ++t) {
            const int r = (wave * 2 + t) * 16;
            int gm = m0 + r + lrow; gm = gm < M ? gm : M - 1;
            const __hip_bfloat16* gp = A + (size_t)gm * K + (k0 + lcol);
            __builtin_amdgcn_global_load_lds(
                (const __attribute__((address_space(1))) void*)gp,
                (__attribute__((address_space(3))) void*)(&As[r][0]),
                16, 0, 0);
        }
#pragma unroll
        for (int t = 0; t < 2; ++t) {
            const int r = (wave * 2 + t) * 16;
            int gn = n0 + r + lrow; gn = gn < N ? gn : N - 1;
            const __hip_bfloat16* gp = Bt + (size_t)gn * K + (k0 + lcol);
            __builtin_amdgcn_global_load_lds(
                (const __attribute__((address_space(1))) void*)gp,
                (__attribute__((address_space(3))) void*)(&Bs[r][0]),
                16, 0, 0);
        }
        __syncthreads();

        bf16x8 af[4], bfv[4];
#pragma unroll
        for (int i = 0; i < 4; ++i)
            af[i] = *(const bf16x8*)(&As[wm + i * 16 + fr][fk]);
#pragma unroll
        for (int j = 0; j < 4; ++j)
            bfv[j] = *(const bf16x8*)(&Bs[wn + j * 16 + fr][fk]);
#pragma unroll
        for (int i = 0; i < 4; ++i)
#pragma unroll
            for (int j = 0; j < 4; ++j)
                acc[i][j] = __builtin_amdgcn_mfma_f32_16x16x32_bf16(
                    af[i], bfv[j], acc[i][j], 0, 0, 0);
    }

    const int rq = (lane >> 4) * 4;
    if (MODE >= 2) {
#pragma unroll
        for (int i = 0; i < 4; ++i) {
#pragma unroll
            for (int r = 0; r < 4; ++r) {
                const int gm = m0 + wm + i * 16 + rq + r;
                if (gm >= M) continue;
                const size_t orow = (size_t)preorder_pos(gm) * ldout;
#pragma unroll
                for (int j = 0; j < 4; ++j) {
                    const int gn = n0 + wn + j * 16 + fr;
                    if (gn < N) {
                        float v = acc[i][j][r] + bias[gn];
                        if (MODE == 2) ((float*)outp)[orow + gn] = v;
                        else ((__hip_bfloat16*)outp)[orow + gn] = __float2bfloat16(v);
                    }
                }
            }
        }
    } else {
        __hip_bfloat16* O = (__hip_bfloat16*)outp;
#pragma unroll
        for (int i = 0; i < 4; ++i) {
#pragma unroll
            for (int r = 0; r < 4; ++r) {
                const int gm = m0 + wm + i * 16 + rq + r;
                if (gm >= M) continue;
#pragma unroll
                for (int j = 0; j < 4; ++j) {
                    const int gn = n0 + wn + j * 16 + fr;
                    if (gn < N) {
                        float v = acc[i][j][r] + bias[gn];
                        if (MODE == 0) v = 1.0f / (1.0f + __expf(-v));
                        O[(size_t)gm * ldout + gn] = __float2bfloat16(v);
                    }
                }
            }
        }
    }
}

// ============================================================================
// 256x256 8-phase GEMM. Schedule = R1 config (harness-verified, best: 684 us).
// NEW (R7): strip-affine XCD grid mapping. Theory: all variants stage 4.03 GB
// and land at ~5.9 TB/s aggregate = per-CU fabric share cap; the fix is L2
// hits. Mapping wg = 128*j + 8*m + k puts n-strip (8j+k) entirely on XCD k
// (dispatch round-robin XCD = wg%8): its 16 m-blocks run concurrently on that
// XCD's CUs -> each 1-MB B strip fetched ONCE into one L2, hit 15x. B fabric
// traffic 1.05 GB -> 131 MB. A (16 MB, read by all XCDs) stays L3-hot.
// Signature if correct: FETCH_SIZE ~200-300 MB (was 595), dur ~420-480 us.
// Tail (strips 120..125) handled densely: wg>=1920 -> r=wg-1920, mt=r/6,
// nt=120+r%6 (96 blocks). Bijective overall (15*128 + 96 = 2016).
// ============================================================================
#define B2M 256
#define B2N 256

template<int MODE>
__global__ __launch_bounds__(512, 2) void gemm256(
    const __hip_bfloat16* __restrict__ A,
    const __hip_bfloat16* __restrict__ Bt,
    const float* __restrict__ bias,
    void* __restrict__ outp,
    int M, int N, int K, int ldout)
{
    __shared__ __align__(16) char smem[131072];

    const int tid  = threadIdx.x;
    const int wave = tid >> 6;
    const int lane = tid & 63;

    // strip-affine XCD mapping (see header comment)
    int mt, nt;
    {
        const int wg = blockIdx.x;
        if (wg < 1920) {
            mt = (wg >> 3) & 15;
            nt = ((wg >> 7) << 3) + (wg & 7);
        } else {
            const int r = wg - 1920;
            mt = r / 6;
            nt = 120 + r % 6;
        }
    }
    const int m0 = mt * B2M;
    const int n0 = nt * B2N;

    const int wm = (wave >> 2) * 128;   // 0 / 128
    const int wn = (wave & 3) * 64;     // 0 / 64 / 128 / 192
    const int nkt = K >> 6;             // # 64-wide K-tiles (even)

    // staging: per-lane pre-swizzled global source
    const int s_row = lane >> 3;                    // 0..7
    const int s_col = ((lane & 7) ^ s_row) * 8;     // bf16 col within 64-col slab

    // fragment read addressing (swizzled)
    const int fr  = lane & 15;
    const int fkq = lane >> 4;                      // 0..3
    const int swz = (fr & 7) << 4;
    const int c0  = (fkq * 16) ^ swz;               // ks=0 col-bytes
    const int c1  = (64 + fkq * 16) ^ swz;          // ks=1 col-bytes
    const int aoff = (wm + fr) * 128;
    const int boff = 32768 + (wn + fr) * 128;

    floatx4 acc[8][4];
#pragma unroll
    for (int i = 0; i < 8; ++i)
#pragma unroll
        for (int j = 0; j < 4; ++j) acc[i][j] = (floatx4)0.0f;

    bf16x8 a0[8], a1[8], b0[4], b1[4];

    auto stage = [&](int bsel, int mat, int h, int kt) {
        const int ktc = kt < nkt ? kt : 0;
        const __hip_bfloat16* gb = mat ? Bt : A;
        const int lim = mat ? N : M;
        const int g0  = mat ? n0 : m0;
#pragma unroll
        for (int inst = 0; inst < 2; ++inst) {
            const int rg = inst * 8 + wave;
            int gr = g0 + h * 128 + rg * 8 + s_row;
            gr = gr < lim ? gr : lim - 1;
            const __hip_bfloat16* gp = gb + (size_t)gr * K + (ktc * 64 + s_col);
            __builtin_amdgcn_global_load_lds(
                (const __attribute__((address_space(1))) void*)gp,
                (__attribute__((address_space(3))) void*)
                    (smem + bsel * 65536 + mat * 32768 + h * 16384 + rg * 1024),
                16, 0, 0);
        }
    };

#define RD_A(dst, bsel, cc) \
    _Pragma("unroll") \
    for (int i = 0; i < 8; ++i) \
        dst[i] = *(const bf16x8*)(smem + (bsel) * 65536 + aoff + i * 2048 + (cc));
#define RD_B(dst, bsel, cc) \
    _Pragma("unroll") \
    for (int j = 0; j < 4; ++j) \
        dst[j] = *(const bf16x8*)(smem + (bsel) * 65536 + boff + j * 2048 + (cc));
#define MM(ib, AA, BB) \
    _Pragma("unroll") \
    for (int i = 0; i < 4; ++i) \
    _Pragma("unroll") \
    for (int j = 0; j < 4; ++j) \
        acc[(ib) + i][j] = __builtin_amdgcn_mfma_f32_16x16x32_bf16( \
            AA[(ib) + i], BB[j], acc[(ib) + i][j], 0, 0, 0);
#define LGKM0  asm volatile("s_waitcnt lgkmcnt(0)" ::: "memory")
#define VM4    asm volatile("s_waitcnt vmcnt(4)" ::: "memory")
#define BAR    __builtin_amdgcn_s_barrier()
#define PRIO1  __builtin_amdgcn_s_setprio(1)
#define PRIO0  __builtin_amdgcn_s_setprio(0)

    // ---- prologue: t0 fully -> buf0; t1 A-halves -> buf1 (stay in flight x2) ----
    stage(0, 0, 0, 0);  // buf0 A-lo  (t0)
    stage(0, 0, 1, 0);  // buf0 A-hi
    stage(0, 1, 0, 0);  // buf0 B-lo
    stage(0, 1, 1, 0);  // buf0 B-hi
    stage(1, 0, 0, 1);  // buf1 A-lo  (t1)
    stage(1, 0, 1, 1);  // buf1 A-hi
    VM4;                // t0's 4 units landed; t1's 2 A-units in flight
    BAR;

#pragma unroll 1
    for (int t = 0; t < nkt; t += 2) {
        // P1
        RD_A(a0, 0, c0); RD_B(b0, 0, c0);
        stage(1, 1, 0, t + 1);              // buf1 B-lo (t+1)
        BAR; LGKM0;
        PRIO1; MM(0, a0, b0); PRIO0;
        BAR;
        // P2
        RD_A(a1, 0, c1); RD_B(b1, 0, c1);
        stage(1, 1, 1, t + 1);              // buf1 B-hi (t+1)
        BAR; LGKM0;
        PRIO1; MM(4, a0, b0); PRIO0;
        BAR;
        // P3 (buf0 reads all complete -> restage A region)
        stage(0, 0, 0, t + 2);              // buf0 A-lo (t+2)
        BAR;
        PRIO1; MM(0, a1, b1); PRIO0;
        BAR;
        // P4
        stage(0, 0, 1, t + 2);              // buf0 A-hi (t+2)
        VM4;                                // t+1 fully landed
        BAR;
        PRIO1; MM(4, a1, b1); PRIO0;
        BAR;
        // P5
        RD_A(a0, 1, c0); RD_B(b0, 1, c0);
        stage(0, 1, 0, t + 2);              // buf0 B-lo (t+2)
        BAR; LGKM0;
        PRIO1; MM(0, a0, b0); PRIO0;
        BAR;
        // P6
        RD_A(a1, 1, c1); RD_B(b1, 1, c1);
        stage(0, 1, 1, t + 2);              // buf0 B-hi (t+2)
        BAR; LGKM0;
        PRIO1; MM(4, a0, b0); PRIO0;
        BAR;
        // P7 (buf1 reads all complete -> restage A region)
        stage(1, 0, 0, t + 3);              // buf1 A-lo (t+3)
        BAR;
        PRIO1; MM(0, a1, b1); PRIO0;
        BAR;
        // P8
        stage(1, 0, 1, t + 3);              // buf1 A-hi (t+3)
        VM4;                                // t+2 fully landed
        BAR;
        PRIO1; MM(4, a1, b1); PRIO0;
        BAR;
    }

#undef RD_A
#undef RD_B
#undef MM
#undef LGKM0
#undef VM4
#undef BAR
#undef PRIO1
#undef PRIO0

    // ---- epilogue: C/D layout col = lane&15, row = (lane>>4)*4 + reg ----
    const int rq = (lane >> 4) * 4;
    if (MODE >= 2) {
#pragma unroll
        for (int i = 0; i < 8; ++i) {
#pragma unroll
            for (int r = 0; r < 4; ++r) {
                const int gm = m0 + wm + i * 16 + rq + r;
                if (gm >= M) continue;
                const size_t orow = (size_t)preorder_pos(gm) * ldout;
#pragma unroll
                for (int j = 0; j < 4; ++j) {
                    const int gn = n0 + wn + j * 16 + fr;
                    if (gn < N) {
                        float v = acc[i][j][r] + bias[gn];
                        if (MODE == 2) ((float*)outp)[orow + gn] = v;
                        else ((__hip_bfloat16*)outp)[orow + gn] = __float2bfloat16(v);
                    }
                }
            }
        }
    } else {
        __hip_bfloat16* O = (__hip_bfloat16*)outp;
#pragma unroll
        for (int i = 0; i < 8; ++i) {
#pragma unroll
            for (int r = 0; r < 4; ++r) {
                const int gm = m0 + wm + i * 16 + rq + r;
                if (gm >= M) continue;
#pragma unroll
                for (int j = 0; j < 4; ++j) {
                    const int gn = n0 + wn + j * 16 + fr;
                    if (gn < N) {
                        float v = acc[i][j][r] + bias[gn];
                        if (MODE == 0) v = 1.0f / (1.0f + __expf(-v));
                        O[(size_t)gm * ldout + gn] = __float2bfloat16(v);
                    }
                }
            }
        }
    }
}

// Small-M GEMM: no LDS, no barriers — loads software-pipeline via vmcnt.
template<int MODE>
__global__ __launch_bounds__(256) void gemm_small(
    const __hip_bfloat16* __restrict__ A,
    const __hip_bfloat16* __restrict__ Bt,
    const float* __restrict__ bias,
    __hip_bfloat16* __restrict__ O,
    int M, int N, int K)
{
    const int wave = threadIdx.x >> 6, lane = threadIdx.x & 63;
    const int n0 = blockIdx.x * 64 + wave * 16;
    const int m0 = blockIdx.y * 16;
    const int fr = lane & 15, fk = (lane >> 4) * 8;

    int am = m0 + fr; am = am < M ? am : M - 1;
    const __hip_bfloat16* ap = A + (size_t)am * K + fk;
    const __hip_bfloat16* bp = Bt + (size_t)(n0 + fr) * K + fk;

    floatx4 acc = (floatx4)0.0f;
#pragma unroll 8
    for (int k0 = 0; k0 < K; k0 += 32) {
        bf16x8 av = *(const bf16x8*)(ap + k0);
        bf16x8 bv = *(const bf16x8*)(bp + k0);
        acc = __builtin_amdgcn_mfma_f32_16x16x32_bf16(av, bv, acc, 0, 0, 0);
    }

    const int rq = (lane >> 4) * 4;
    const int gn = n0 + fr;
    const float b = bias[gn];
#pragma unroll
    for (int r = 0; r < 4; ++r) {
        const int gm = m0 + rq + r;
        if (gm >= M) continue;
        float v = acc[r] + b;
        if (MODE == 0) v = 1.0f / (1.0f + __expf(-v));
        O[(size_t)gm * N + gn] = __float2bfloat16(v);
    }
}

// in [R,C] f32 row-major -> outT [C,R] bf16 row-major. 64x64 tiles.
__global__ __launch_bounds__(256) void transpose_to_bf16(
    const float* __restrict__ in, __hip_bfloat16* __restrict__ outT, int R, int C)
{
    __shared__ float tile[64][65];
    const int c0 = blockIdx.x * 64, r0 = blockIdx.y * 64;
    const int tx = threadIdx.x & 63, ty = threadIdx.x >> 6;
#pragma unroll
    for (int i = 0; i < 64; i += 4) {
        int r = r0 + ty + i, c = c0 + tx;
        tile[ty + i][tx] = (r < R && c < C) ? in[(size_t)r * C + c] : 0.0f;
    }
    __syncthreads();
#pragma unroll
    for (int i = 0; i < 64; i += 4) {
        int rr = c0 + ty + i, cc = r0 + tx;
        if (rr < C && cc < R) outT[(size_t)rr * R + cc] = __float2bfloat16(tile[tx][ty + i]);
    }
}

__global__ __launch_bounds__(256) void convert_root(
    const float* __restrict__ in, __hip_bfloat16* __restrict__ out)
{
    int i = blockIdx.x * 256 + threadIdx.x;
    if (i < HDIM) out[i] = __float2bfloat16(in[i]);
}

// Log-softmax over bf16 logit rows (stride LDV), writing fp32 rows (stride VDIM).
__global__ __launch_bounds__(256) void logsoftmax_bf16(
    const unsigned short* __restrict__ L, float* __restrict__ O)
{
    extern __shared__ char smem[];
    unsigned short* rb = (unsigned short*)smem;
    float* wred = (float*)(smem + 64016);
    const int tid = threadIdx.x, lane = tid & 63, wv = tid >> 6;
    const unsigned short* src = L + (size_t)blockIdx.x * LDV;

    float m = -3.0e38f;
    for (int j = tid * 8; j < 32000; j += 2048) {
        ushort8 u = *(const ushort8*)(src + j);
        *(ushort8*)(rb + j) = u;
#pragma unroll
        for (int t = 0; t < 8; ++t) m = fmaxf(m, bf2f(u[t]));
    }
    if (tid == 0) { unsigned short u = src[32000]; rb[32000] = u; m = fmaxf(m, bf2f(u)); }
#pragma unroll
    for (int off = 32; off; off >>= 1) m = fmaxf(m, __shfl_xor(m, off, 64));
    if (lane == 0) wred[wv] = m;
    __syncthreads();
    const float M4 = fmaxf(fmaxf(wred[0], wred[1]), fmaxf(wred[2], wred[3]));

    float s = 0.0f;
    for (int j = tid * 8; j < 32000; j += 2048) {
        ushort8 u = *(const ushort8*)(rb + j);
#pragma unroll
        for (int t = 0; t < 8; ++t) s += __expf(bf2f(u[t]) - M4);
    }
    if (tid == 0) s += __expf(bf2f(rb[32000]) - M4);
#pragma unroll
    for (int off = 32; off; off >>= 1) s += __shfl_xor(s, off, 64);
    if (lane == 0) wred[4 + wv] = s;
    __syncthreads();
    const float lse = M4 + __logf(wred[4] + wred[5] + wred[6] + wred[7]);

    float* dst = O + (size_t)blockIdx.x * VDIM;
    for (int j = tid * 8; j < 32000; j += 2048) {
        ushort8 u = *(const ushort8*)(rb + j);
#pragma unroll
        for (int t = 0; t < 8; ++t) dst[j + t] = bf2f(u[t]) - lse;
    }
    if (tid == 0) dst[32000] = bf2f(rb[32000]) - lse;
}

// Fallback: in-place fp32 log_softmax (used only if ws too small for bf16 logits).
__global__ __launch_bounds__(256) void logsoftmax_rows(float* __restrict__ O, int n)
{
    __shared__ float sm[256], ssum[256];
    const int tid = threadIdx.x;
    float* p = O + (size_t)blockIdx.x * n;
    float m = -3.0e38f, s = 0.0f;
    for (int j = tid; j < n; j += 256) {
        float x = p[j];
        float nm = fmaxf(m, x);
        s = s * __expf(m - nm) + __expf(x - nm);
        m = nm;
    }
    sm[tid] = m; ssum[tid] = s;
    __syncthreads();
    for (int off = 128; off > 0; off >>= 1) {
        if (tid < off) {
            float m2 = sm[tid + off], s2 = ssum[tid + off];
            float nm = fmaxf(sm[tid], m2);
            ssum[tid] = ssum[tid] * __expf(sm[tid] - nm) + s2 * __expf(m2 - nm);
            sm[tid] = nm;
        }
        __syncthreads();
    }
    const float lse = sm[0] + __logf(ssum[0]);
    for (int j = tid; j < n; j += 256) p[j] -= lse;
}

extern "C" void kernel_launch(void* const* d_in, const int* in_sizes, int n_in,
                              void* d_out, int out_size, void* d_ws, size_t ws_size,
                              hipStream_t stream)
{
    const float* root = (const float*)d_in[0];
    const float* W1v  = (const float*)d_in[1];   // [1024, 2048]
    const float* b1v  = (const float*)d_in[2];
    const float* W2v  = (const float*)d_in[3];   // [2048, 32001]
    const float* b2v  = (const float*)d_in[4];
    const float* W1c  = (const float*)d_in[5];   // [1024, 2048]
    const float* b1c  = (const float*)d_in[6];
    const float* W2c  = (const float*)d_in[7];   // [2048, 2048]
    const float* b2c  = (const float*)d_in[8];

    char* ws = (char*)d_ws;
    __hip_bfloat16* Hall = (__hip_bfloat16*)(ws + 0);             // 4095x1024 (8 MB rgn)
    __hip_bfloat16* X1   = (__hip_bfloat16*)(ws +   8388608ull);  // 4095x2048 (16 MB rgn)
    __hip_bfloat16* Tt   = (__hip_bfloat16*)(ws +  25165824ull);  // 1024x2048 (4 MB)
    __hip_bfloat16* W1vT = (__hip_bfloat16*)(ws +  29360128ull);  // 2048x1024 (4 MB)
    __hip_bfloat16* W1cT = (__hip_bfloat16*)(ws +  33554432ull);  // 2048x1024 (4 MB)
    __hip_bfloat16* W2cT = (__hip_bfloat16*)(ws +  37748736ull);  // 2048x2048 (8 MB)
    __hip_bfloat16* W2vT = (__hip_bfloat16*)(ws +  46137344ull);  // 32001x2048 (ends 177,213,440)
    __hip_bfloat16* Lb   = (__hip_bfloat16*)(ws + 177213440ull);  // 4095xLDV bf16 logits
    const bool bf16_logits = ws_size >= 177213440ull + (size_t)NNODES * LDV * 2;

    dim3 blk(256);

    transpose_to_bf16<<<dim3( 32, 16), blk, 0, stream>>>(W1v, W1vT, 1024, 2048);
    transpose_to_bf16<<<dim3(501, 32), blk, 0, stream>>>(W2v, W2vT, 2048, VDIM);
    transpose_to_bf16<<<dim3( 32, 16), blk, 0, stream>>>(W1c, W1cT, 1024, 2048);
    transpose_to_bf16<<<dim3( 32, 32), blk, 0, stream>>>(W2c, W2cT, 2048, 2048);
    convert_root<<<dim3(4), blk, 0, stream>>>(root, Hall);

    // Child phase: level d -> d+1.
    for (int d = 0; d < DEPTH_T; ++d) {
        const int Md = 1 << d;
        __hip_bfloat16* Hd = Hall + (size_t)(Md - 1) * HDIM;
        __hip_bfloat16* Hn = Hall + (size_t)((2 << d) - 1) * HDIM;
        if (Md <= 256) {
            dim3 g(32, (Md + 15) / 16);
            gemm_small<0><<<g, blk, 0, stream>>>(Hd, W1cT, b1c, Tt, Md, 2048, 1024);
            gemm_small<1><<<g, blk, 0, stream>>>(Tt, W2cT, b2c, Hn, Md, 2048, 2048);
        } else {
            dim3 g(16, Md / 128);
            gemm_bt<0, false><<<g, blk, 0, stream>>>(Hd, W1cT, b1c, Tt, Md, 2048, 1024, 2048);
            gemm_bt<1, false><<<g, blk, 0, stream>>>(Tt, W2cT, b2c, Hn, Md, 2048, 2048, 2048);
        }
    }

    // Value phase.
    gemm_bt<0, false><<<dim3(16, 32), blk, 0, stream>>>(Hall, W1vT, b1v, X1, NNODES, 2048, 1024, 2048);
    if (bf16_logits) {
        // 1-D grid, strip-affine XCD mapping inside the kernel
        gemm256<3><<<dim3(16 * 126), dim3(512), 0, stream>>>(X1, W2vT, b2v, Lb, NNODES, VDIM, 2048, LDV);
        logsoftmax_bf16<<<dim3(NNODES), blk, 64048, stream>>>((const unsigned short*)Lb, (float*)d_out);
    } else {
        gemm_bt<2, true><<<dim3(32, 251), blk, 0, stream>>>(X1, W2vT, b2v, d_out, NNODES, VDIM, 2048, VDIM);
        logsoftmax_rows<<<dim3(NNODES), blk, 0, stream>>>((float*)d_out, VDIM);
    }
}

// Round 8
// 1440.137 us; speedup vs baseline: 1.2947x; 1.0091x over previous
//
#include <hip/hip_runtime.h>
#include <hip/hip_bf16.h>

#define DEPTH_T 11
#define HDIM 1024
#define VDIM 32001
#define NNODES 4095   // 2^12 - 1
#define LDV 32008     // padded bf16 logit row stride (x2B = 64016, 16B-aligned)

typedef __attribute__((ext_vector_type(8))) short bf16x8;
typedef __attribute__((ext_vector_type(8))) unsigned short ushort8;
typedef __attribute__((ext_vector_type(4))) float floatx4;

// Pre-order position of BFS/heap node m (0-based), perfect binary tree depth DEPTH_T.
__device__ __forceinline__ int preorder_pos(int m) {
    int q = m + 1;
    int d = 31 - __clz(q);
    int pos = 0;
    for (int i = 1; i <= d; ++i) {
        int b = (q >> (d - i)) & 1;
        pos += 1 + b * ((1 << (DEPTH_T - i + 1)) - 1);
    }
    return pos;
}

__device__ __forceinline__ float bf2f(unsigned short u) {
    return __uint_as_float(((unsigned)u) << 16);
}

#define BM 128
#define BN 128
#define BK 32

// C = A [M,K] @ Bt^T (Bt is [N,K] bf16 row-major) + bias[N]
// MODE 0: bf16 out = sigmoid(acc+bias)        MODE 1: bf16 out = acc+bias
// MODE 2: f32 out, rows scattered by preorder  MODE 3: bf16 out, rows scattered
template<int MODE, bool SWAPG>
__global__ __launch_bounds__(256, 2) void gemm_bt(
    const __hip_bfloat16* __restrict__ A,
    const __hip_bfloat16* __restrict__ Bt,
    const float* __restrict__ bias,
    void* __restrict__ outp,
    int M, int N, int K, int ldout)
{
    __shared__ __align__(16) __hip_bfloat16 As[BM][BK];
    __shared__ __align__(16) __hip_bfloat16 Bs[BN][BK];

    const int tid  = threadIdx.x;
    const int wave = tid >> 6;
    const int lane = tid & 63;
    const int m0 = (SWAPG ? blockIdx.x : blockIdx.y) * BM;
    const int n0 = (SWAPG ? blockIdx.y : blockIdx.x) * BN;
    const int wm = (wave & 1) * 64;
    const int wn = (wave >> 1) * 64;

    floatx4 acc[4][4];
#pragma unroll
    for (int i = 0; i < 4; ++i)
#pragma unroll
        for (int j = 0; j < 4; ++j) acc[i][j] = (floatx4)0.0f;

    const int lrow = lane >> 2;
    const int lcol = (lane & 3) * 8;
    const int fr = lane & 15;
    const int fk = (lane >> 4) * 8;

    for (int k0 = 0; k0 < K; k0 += BK) {
        __syncthreads();
#pragma unroll
        for (int t = 0; t < 2; ++t) {
            const int r = (wave * 2 + t) * 16;
            int gm = m0 + r + lrow; gm = gm < M ? gm : M - 1;
            const __hip_bfloat16* gp = A + (size_t)gm * K + (k0 + lcol);
            __builtin_amdgcn_global_load_lds(
                (const __attribute__((address_space(1))) void*)gp,
                (__attribute__((address_space(3))) void*)(&As[r][0]),
                16, 0, 0);
        }
#pragma unroll
        for (int t = 0; t < 2; ++t) {
            const int r = (wave * 2 + t) * 16;
            int gn = n0 + r + lrow; gn = gn < N ? gn : N - 1;
            const __hip_bfloat16* gp = Bt + (size_t)gn * K + (k0 + lcol);
            __builtin_amdgcn_global_load_lds(
                (const __attribute__((address_space(1))) void*)gp,
                (__attribute__((address_space(3))) void*)(&Bs[r][0]),
                16, 0, 0);
        }
        __syncthreads();

        bf16x8 af[4], bfv[4];
#pragma unroll
        for (int i = 0; i < 4; ++i)
            af[i] = *(const bf16x8*)(&As[wm + i * 16 + fr][fk]);
#pragma unroll
        for (int j = 0; j < 4; ++j)
            bfv[j] = *(const bf16x8*)(&Bs[wn + j * 16 + fr][fk]);
#pragma unroll
        for (int i = 0; i < 4; ++i)
#pragma unroll
            for (int j = 0; j < 4; ++j)
                acc[i][j] = __builtin_amdgcn_mfma_f32_16x16x32_bf16(
                    af[i], bfv[j], acc[i][j], 0, 0, 0);
    }

    const int rq = (lane >> 4) * 4;
    if (MODE >= 2) {
#pragma unroll
        for (int i = 0; i < 4; ++i) {
#pragma unroll
            for (int r = 0; r < 4; ++r) {
                const int gm = m0 + wm + i * 16 + rq + r;
                if (gm >= M) continue;
                const size_t orow = (size_t)preorder_pos(gm) * ldout;
#pragma unroll
                for (int j = 0; j < 4; ++j) {
                    const int gn = n0 + wn + j * 16 + fr;
                    if (gn < N) {
                        float v = acc[i][j][r] + bias[gn];
                        if (MODE == 2) ((float*)outp)[orow + gn] = v;
                        else ((__hip_bfloat16*)outp)[orow + gn] = __float2bfloat16(v);
                    }
                }
            }
        }
    } else {
        __hip_bfloat16* O = (__hip_bfloat16*)outp;
#pragma unroll
        for (int i = 0; i < 4; ++i) {
#pragma unroll
            for (int r = 0; r < 4; ++r) {
                const int gm = m0 + wm + i * 16 + rq + r;
                if (gm >= M) continue;
#pragma unroll
                for (int j = 0; j < 4; ++j) {
                    const int gn = n0 + wn + j * 16 + fr;
                    if (gn < N) {
                        float v = acc[i][j][r] + bias[gn];
                        if (MODE == 0) v = 1.0f / (1.0f + __expf(-v));
                        O[(size_t)gm * ldout + gn] = __float2bfloat16(v);
                    }
                }
            }
        }
    }
}

// ============================================================================
// 256x256 8-phase GEMM. Schedule = R1 config (harness-verified, best: 680 us).
// R8 changes (schedule untouched):
//  1) Balanced brick mapping: padded 2048-block grid; generation g (256
//     blocks) covers an 8m x 32n brick; XCD k = i&7 gets a 4m x 8n sub-brick
//     -> unique panels per XCD per iter = 4 A + 8 B = 12 (all prior mappings:
//     18). First mapping that reduces the L2 miss set.
//       g=wg>>8, i=wg&255, k=i&7, s=i>>3
//       mt=(k&1)*4+(s&3)+(g&1)*8 ; nt=(k>>1)*8+(s>>2)+(g>>1)*32 ; exit nt>=nwy
//     Bijective over 16 x 128 (verified); nt 126/127 early-exit.
//  2) VALU diet: 8 per-unit staging base addresses (64-bit mul + row clamp)
//     hoisted out of the K-loop; per stage call = shared ktc*64 + ptr add.
//     (VALU and MFMA share the SIMD issue port: VALUBusy 28 + MfmaUtil 34.)
// ============================================================================
#define B2M 256
#define B2N 256

template<int MODE>
__global__ __launch_bounds__(512, 2) void gemm256(
    const __hip_bfloat16* __restrict__ A,
    const __hip_bfloat16* __restrict__ Bt,
    const float* __restrict__ bias,
    void* __restrict__ outp,
    int M, int N, int K, int ldout)
{
    __shared__ __align__(16) char smem[131072];

    const int tid  = threadIdx.x;
    const int wave = tid >> 6;
    const int lane = tid & 63;

    // balanced brick mapping (padded grid; see header)
    const int nwy = (N + B2N - 1) / B2N;
    int mt, nt;
    {
        const int g = blockIdx.x >> 8;
        const int i = blockIdx.x & 255;
        const int k = i & 7, s = i >> 3;
        mt = (k & 1) * 4 + (s & 3) + (g & 1) * 8;
        nt = (k >> 1) * 8 + (s >> 2) + (g >> 1) * 32;
    }
    if (nt >= nwy) return;          // padded tail (uniform per block, pre-barrier)
    const int m0 = mt * B2M;
    const int n0 = nt * B2N;

    const int wm = (wave >> 2) * 128;   // 0 / 128
    const int wn = (wave & 3) * 64;     // 0 / 64 / 128 / 192
    const int nkt = K >> 6;             // # 64-wide K-tiles (even)

    // staging: per-lane pre-swizzled global source
    const int s_row = lane >> 3;                    // 0..7
    const int s_col = ((lane & 7) ^ s_row) * 8;     // bf16 col within 64-col slab

    // fragment read addressing (swizzled)
    const int fr  = lane & 15;
    const int fkq = lane >> 4;                      // 0..3
    const int swz = (fr & 7) << 4;
    const int c0  = (fkq * 16) ^ swz;               // ks=0 col-bytes
    const int c1  = (64 + fkq * 16) ^ swz;          // ks=1 col-bytes
    const int aoff = (wm + fr) * 128;
    const int boff = 32768 + (wn + fr) * 128;

    floatx4 acc[8][4];
#pragma unroll
    for (int i = 0; i < 8; ++i)
#pragma unroll
        for (int j = 0; j < 4; ++j) acc[i][j] = (floatx4)0.0f;

    bf16x8 a0[8], a1[8], b0[4], b1[4];

    // hoisted per-unit staging bases (global addr never depended on bsel)
    auto mkb = [&](const __hip_bfloat16* gb, int g0, int lim, int h, int inst) {
        int gr = g0 + h * 128 + (inst * 8 + wave) * 8 + s_row;
        gr = gr < lim ? gr : lim - 1;
        return gb + (size_t)gr * K + s_col;
    };
    const __hip_bfloat16* pA00 = mkb(A,  m0, M, 0, 0);
    const __hip_bfloat16* pA01 = mkb(A,  m0, M, 0, 1);
    const __hip_bfloat16* pA10 = mkb(A,  m0, M, 1, 0);
    const __hip_bfloat16* pA11 = mkb(A,  m0, M, 1, 1);
    const __hip_bfloat16* pB00 = mkb(Bt, n0, N, 0, 0);
    const __hip_bfloat16* pB01 = mkb(Bt, n0, N, 0, 1);
    const __hip_bfloat16* pB10 = mkb(Bt, n0, N, 1, 0);
    const __hip_bfloat16* pB11 = mkb(Bt, n0, N, 1, 1);

#define STAGE(bsel, mat, h, PP0, PP1, kt) do { \
    const int ko_ = ((kt) < nkt ? (kt) : 0) * 64; \
    __builtin_amdgcn_global_load_lds( \
        (const __attribute__((address_space(1))) void*)((PP0) + ko_), \
        (__attribute__((address_space(3))) void*) \
            (smem + (bsel)*65536 + (mat)*32768 + (h)*16384 + wave*1024), 16, 0, 0); \
    __builtin_amdgcn_global_load_lds( \
        (const __attribute__((address_space(1))) void*)((PP1) + ko_), \
        (__attribute__((address_space(3))) void*) \
            (smem + (bsel)*65536 + (mat)*32768 + (h)*16384 + 8192 + wave*1024), 16, 0, 0); \
} while (0)

#define RD_A(dst, bsel, cc) \
    _Pragma("unroll") \
    for (int i = 0; i < 8; ++i) \
        dst[i] = *(const bf16x8*)(smem + (bsel) * 65536 + aoff + i * 2048 + (cc));
#define RD_B(dst, bsel, cc) \
    _Pragma("unroll") \
    for (int j = 0; j < 4; ++j) \
        dst[j] = *(const bf16x8*)(smem + (bsel) * 65536 + boff + j * 2048 + (cc));
#define MM(ib, AA, BB) \
    _Pragma("unroll") \
    for (int i = 0; i < 4; ++i) \
    _Pragma("unroll") \
    for (int j = 0; j < 4; ++j) \
        acc[(ib) + i][j] = __builtin_amdgcn_mfma_f32_16x16x32_bf16( \
            AA[(ib) + i], BB[j], acc[(ib) + i][j], 0, 0, 0);
#define LGKM0  asm volatile("s_waitcnt lgkmcnt(0)" ::: "memory")
#define VM4    asm volatile("s_waitcnt vmcnt(4)" ::: "memory")
#define BAR    __builtin_amdgcn_s_barrier()
#define PRIO1  __builtin_amdgcn_s_setprio(1)
#define PRIO0  __builtin_amdgcn_s_setprio(0)

    // ---- prologue: t0 fully -> buf0; t1 A-halves -> buf1 (stay in flight x2) ----
    STAGE(0, 0, 0, pA00, pA01, 0);  // buf0 A-lo  (t0)
    STAGE(0, 0, 1, pA10, pA11, 0);  // buf0 A-hi
    STAGE(0, 1, 0, pB00, pB01, 0);  // buf0 B-lo
    STAGE(0, 1, 1, pB10, pB11, 0);  // buf0 B-hi
    STAGE(1, 0, 0, pA00, pA01, 1);  // buf1 A-lo  (t1)
    STAGE(1, 0, 1, pA10, pA11, 1);  // buf1 A-hi
    VM4;                // t0's 4 units landed; t1's 2 A-units in flight
    BAR;

#pragma unroll 1
    for (int t = 0; t < nkt; t += 2) {
        // P1
        RD_A(a0, 0, c0); RD_B(b0, 0, c0);
        STAGE(1, 1, 0, pB00, pB01, t + 1);  // buf1 B-lo (t+1)
        BAR; LGKM0;
        PRIO1; MM(0, a0, b0); PRIO0;
        BAR;
        // P2
        RD_A(a1, 0, c1); RD_B(b1, 0, c1);
        STAGE(1, 1, 1, pB10, pB11, t + 1);  // buf1 B-hi (t+1)
        BAR; LGKM0;
        PRIO1; MM(4, a0, b0); PRIO0;
        BAR;
        // P3 (buf0 reads all complete -> restage A region)
        STAGE(0, 0, 0, pA00, pA01, t + 2);  // buf0 A-lo (t+2)
        BAR;
        PRIO1; MM(0, a1, b1); PRIO0;
        BAR;
        // P4
        STAGE(0, 0, 1, pA10, pA11, t + 2);  // buf0 A-hi (t+2)
        VM4;                                // t+1 fully landed
        BAR;
        PRIO1; MM(4, a1, b1); PRIO0;
        BAR;
        // P5
        RD_A(a0, 1, c0); RD_B(b0, 1, c0);
        STAGE(0, 1, 0, pB00, pB01, t + 2);  // buf0 B-lo (t+2)
        BAR; LGKM0;
        PRIO1; MM(0, a0, b0); PRIO0;
        BAR;
        // P6
        RD_A(a1, 1, c1); RD_B(b1, 1, c1);
        STAGE(0, 1, 1, pB10, pB11, t + 2);  // buf0 B-hi (t+2)
        BAR; LGKM0;
        PRIO1; MM(4, a0, b0); PRIO0;
        BAR;
        // P7 (buf1 reads all complete -> restage A region)
        STAGE(1, 0, 0, pA00, pA01, t + 3);  // buf1 A-lo (t+3)
        BAR;
        PRIO1; MM(0, a1, b1); PRIO0;
        BAR;
        // P8
        STAGE(1, 0, 1, pA10, pA11, t + 3);  // buf1 A-hi (t+3)
        VM4;                                // t+2 fully landed
        BAR;
        PRIO1; MM(4, a1, b1); PRIO0;
        BAR;
    }

#undef STAGE
#undef RD_A
#undef RD_B
#undef MM
#undef LGKM0
#undef VM4
#undef BAR
#undef PRIO1
#undef PRIO0

    // ---- epilogue: C/D layout col = lane&15, row = (lane>>4)*4 + reg ----
    const int rq = (lane >> 4) * 4;
    if (MODE >= 2) {
#pragma unroll
        for (int i = 0; i < 8; ++i) {
#pragma unroll
            for (int r = 0; r < 4; ++r) {
                const int gm = m0 + wm + i * 16 + rq + r;
                if (gm >= M) continue;
                const size_t orow = (size_t)preorder_pos(gm) * ldout;
#pragma unroll
                for (int j = 0; j < 4; ++j) {
                    const int gn = n0 + wn + j * 16 + fr;
                    if (gn < N) {
                        float v = acc[i][j][r] + bias[gn];
                        if (MODE == 2) ((float*)outp)[orow + gn] = v;
                        else ((__hip_bfloat16*)outp)[orow + gn] = __float2bfloat16(v);
                    }
                }
            }
        }
    } else {
        __hip_bfloat16* O = (__hip_bfloat16*)outp;
#pragma unroll
        for (int i = 0; i < 8; ++i) {
#pragma unroll
            for (int r = 0; r < 4; ++r) {
                const int gm = m0 + wm + i * 16 + rq + r;
                if (gm >= M) continue;
#pragma unroll
                for (int j = 0; j < 4; ++j) {
                    const int gn = n0 + wn + j * 16 + fr;
                    if (gn < N) {
                        float v = acc[i][j][r] + bias[gn];
                        if (MODE == 0) v = 1.0f / (1.0f + __expf(-v));
                        O[(size_t)gm * ldout + gn] = __float2bfloat16(v);
                    }
                }
            }
        }
    }
}

// Small-M GEMM: no LDS, no barriers — loads software-pipeline via vmcnt.
template<int MODE>
__global__ __launch_bounds__(256) void gemm_small(
    const __hip_bfloat16* __restrict__ A,
    const __hip_bfloat16* __restrict__ Bt,
    const float* __restrict__ bias,
    __hip_bfloat16* __restrict__ O,
    int M, int N, int K)
{
    const int wave = threadIdx.x >> 6, lane = threadIdx.x & 63;
    const int n0 = blockIdx.x * 64 + wave * 16;
    const int m0 = blockIdx.y * 16;
    const int fr = lane & 15, fk = (lane >> 4) * 8;

    int am = m0 + fr; am = am < M ? am : M - 1;
    const __hip_bfloat16* ap = A + (size_t)am * K + fk;
    const __hip_bfloat16* bp = Bt + (size_t)(n0 + fr) * K + fk;

    floatx4 acc = (floatx4)0.0f;
#pragma unroll 8
    for (int k0 = 0; k0 < K; k0 += 32) {
        bf16x8 av = *(const bf16x8*)(ap + k0);
        bf16x8 bv = *(const bf16x8*)(bp + k0);
        acc = __builtin_amdgcn_mfma_f32_16x16x32_bf16(av, bv, acc, 0, 0, 0);
    }

    const int rq = (lane >> 4) * 4;
    const int gn = n0 + fr;
    const float b = bias[gn];
#pragma unroll
    for (int r = 0; r < 4; ++r) {
        const int gm = m0 + rq + r;
        if (gm >= M) continue;
        float v = acc[r] + b;
        if (MODE == 0) v = 1.0f / (1.0f + __expf(-v));
        O[(size_t)gm * N + gn] = __float2bfloat16(v);
    }
}

// in [R,C] f32 row-major -> outT [C,R] bf16 row-major. 64x64 tiles.
__global__ __launch_bounds__(256) void transpose_to_bf16(
    const float* __restrict__ in, __hip_bfloat16* __restrict__ outT, int R, int C)
{
    __shared__ float tile[64][65];
    const int c0 = blockIdx.x * 64, r0 = blockIdx.y * 64;
    const int tx = threadIdx.x & 63, ty = threadIdx.x >> 6;
#pragma unroll
    for (int i = 0; i < 64; i += 4) {
        int r = r0 + ty + i, c = c0 + tx;
        tile[ty + i][tx] = (r < R && c < C) ? in[(size_t)r * C + c] : 0.0f;
    }
    __syncthreads();
#pragma unroll
    for (int i = 0; i < 64; i += 4) {
        int rr = c0 + ty + i, cc = r0 + tx;
        if (rr < C && cc < R) outT[(size_t)rr * R + cc] = __float2bfloat16(tile[tx][ty + i]);
    }
}

__global__ __launch_bounds__(256) void convert_root(
    const float* __restrict__ in, __hip_bfloat16* __restrict__ out)
{
    int i = blockIdx.x * 256 + threadIdx.x;
    if (i < HDIM) out[i] = __float2bfloat16(in[i]);
}

// Log-softmax over bf16 logit rows (stride LDV), writing fp32 rows (stride VDIM).
__global__ __launch_bounds__(256) void logsoftmax_bf16(
    const unsigned short* __restrict__ L, float* __restrict__ O)
{
    extern __shared__ char smem[];
    unsigned short* rb = (unsigned short*)smem;
    float* wred = (float*)(smem + 64016);
    const int tid = threadIdx.x, lane = tid & 63, wv = tid >> 6;
    const unsigned short* src = L + (size_t)blockIdx.x * LDV;

    float m = -3.0e38f;
    for (int j = tid * 8; j < 32000; j += 2048) {
        ushort8 u = *(const ushort8*)(src + j);
        *(ushort8*)(rb + j) = u;
#pragma unroll
        for (int t = 0; t < 8; ++t) m = fmaxf(m, bf2f(u[t]));
    }
    if (tid == 0) { unsigned short u = src[32000]; rb[32000] = u; m = fmaxf(m, bf2f(u)); }
#pragma unroll
    for (int off = 32; off; off >>= 1) m = fmaxf(m, __shfl_xor(m, off, 64));
    if (lane == 0) wred[wv] = m;
    __syncthreads();
    const float M4 = fmaxf(fmaxf(wred[0], wred[1]), fmaxf(wred[2], wred[3]));

    float s = 0.0f;
    for (int j = tid * 8; j < 32000; j += 2048) {
        ushort8 u = *(const ushort8*)(rb + j);
#pragma unroll
        for (int t = 0; t < 8; ++t) s += __expf(bf2f(u[t]) - M4);
    }
    if (tid == 0) s += __expf(bf2f(rb[32000]) - M4);
#pragma unroll
    for (int off = 32; off; off >>= 1) s += __shfl_xor(s, off, 64);
    if (lane == 0) wred[4 + wv] = s;
    __syncthreads();
    const float lse = M4 + __logf(wred[4] + wred[5] + wred[6] + wred[7]);

    float* dst = O + (size_t)blockIdx.x * VDIM;
    for (int j = tid * 8; j < 32000; j += 2048) {
        ushort8 u = *(const ushort8*)(rb + j);
#pragma unroll
        for (int t = 0; t < 8; ++t) dst[j + t] = bf2f(u[t]) - lse;
    }
    if (tid == 0) dst[32000] = bf2f(rb[32000]) - lse;
}

// Fallback: in-place fp32 log_softmax (used only if ws too small for bf16 logits).
__global__ __launch_bounds__(256) void logsoftmax_rows(float* __restrict__ O, int n)
{
    __shared__ float sm[256], ssum[256];
    const int tid = threadIdx.x;
    float* p = O + (size_t)blockIdx.x * n;
    float m = -3.0e38f, s = 0.0f;
    for (int j = tid; j < n; j += 256) {
        float x = p[j];
        float nm = fmaxf(m, x);
        s = s * __expf(m - nm) + __expf(x - nm);
        m = nm;
    }
    sm[tid] = m; ssum[tid] = s;
    __syncthreads();
    for (int off = 128; off > 0; off >>= 1) {
        if (tid < off) {
            float m2 = sm[tid + off], s2 = ssum[tid + off];
            float nm = fmaxf(sm[tid], m2);
            ssum[tid] = ssum[tid] * __expf(sm[tid] - nm) + s2 * __expf(m2 - nm);
            sm[tid] = nm;
        }
        __syncthreads();
    }
    const float lse = sm[0] + __logf(ssum[0]);
    for (int j = tid; j < n; j += 256) p[j] -= lse;
}

extern "C" void kernel_launch(void* const* d_in, const int* in_sizes, int n_in,
                              void* d_out, int out_size, void* d_ws, size_t ws_size,
                              hipStream_t stream)
{
    const float* root = (const float*)d_in[0];
    const float* W1v  = (const float*)d_in[1];   // [1024, 2048]
    const float* b1v  = (const float*)d_in[2];
    const float* W2v  = (const float*)d_in[3];   // [2048, 32001]
    const float* b2v  = (const float*)d_in[4];
    const float* W1c  = (const float*)d_in[5];   // [1024, 2048]
    const float* b1c  = (const float*)d_in[6];
    const float* W2c  = (const float*)d_in[7];   // [2048, 2048]
    const float* b2c  = (const float*)d_in[8];

    char* ws = (char*)d_ws;
    __hip_bfloat16* Hall = (__hip_bfloat16*)(ws + 0);             // 4095x1024 (8 MB rgn)
    __hip_bfloat16* X1   = (__hip_bfloat16*)(ws +   8388608ull);  // 4095x2048 (16 MB rgn)
    __hip_bfloat16* Tt   = (__hip_bfloat16*)(ws +  25165824ull);  // 1024x2048 (4 MB)
    __hip_bfloat16* W1vT = (__hip_bfloat16*)(ws +  29360128ull);  // 2048x1024 (4 MB)
    __hip_bfloat16* W1cT = (__hip_bfloat16*)(ws +  33554432ull);  // 2048x1024 (4 MB)
    __hip_bfloat16* W2cT = (__hip_bfloat16*)(ws +  37748736ull);  // 2048x2048 (8 MB)
    __hip_bfloat16* W2vT = (__hip_bfloat16*)(ws +  46137344ull);  // 32001x2048 (ends 177,213,440)
    __hip_bfloat16* Lb   = (__hip_bfloat16*)(ws + 177213440ull);  // 4095xLDV bf16 logits
    const bool bf16_logits = ws_size >= 177213440ull + (size_t)NNODES * LDV * 2;

    dim3 blk(256);

    transpose_to_bf16<<<dim3( 32, 16), blk, 0, stream>>>(W1v, W1vT, 1024, 2048);
    transpose_to_bf16<<<dim3(501, 32), blk, 0, stream>>>(W2v, W2vT, 2048, VDIM);
    transpose_to_bf16<<<dim3( 32, 16), blk, 0, stream>>>(W1c, W1cT, 1024, 2048);
    transpose_to_bf16<<<dim3( 32, 32), blk, 0, stream>>>(W2c, W2cT, 2048, 2048);
    convert_root<<<dim3(4), blk, 0, stream>>>(root, Hall);

    // Child phase: level d -> d+1.
    for (int d = 0; d < DEPTH_T; ++d) {
        const int Md = 1 << d;
        __hip_bfloat16* Hd = Hall + (size_t)(Md - 1) * HDIM;
        __hip_bfloat16* Hn = Hall + (size_t)((2 << d) - 1) * HDIM;
        if (Md <= 256) {
            dim3 g(32, (Md + 15) / 16);
            gemm_small<0><<<g, blk, 0, stream>>>(Hd, W1cT, b1c, Tt, Md, 2048, 1024);
            gemm_small<1><<<g, blk, 0, stream>>>(Tt, W2cT, b2c, Hn, Md, 2048, 2048);
        } else {
            dim3 g(16, Md / 128);
            gemm_bt<0, false><<<g, blk, 0, stream>>>(Hd, W1cT, b1c, Tt, Md, 2048, 1024, 2048);
            gemm_bt<1, false><<<g, blk, 0, stream>>>(Tt, W2cT, b2c, Hn, Md, 2048, 2048, 2048);
        }
    }

    // Value phase.
    gemm_bt<0, false><<<dim3(16, 32), blk, 0, stream>>>(Hall, W1vT, b1v, X1, NNODES, 2048, 1024, 2048);
    if (bf16_logits) {
        // padded 1-D grid; balanced brick XCD mapping inside the kernel
        gemm256<3><<<dim3(2048), dim3(512), 0, stream>>>(X1, W2vT, b2v, Lb, NNODES, VDIM, 2048, LDV);
        logsoftmax_bf16<<<dim3(NNODES), blk, 64048, stream>>>((const unsigned short*)Lb, (float*)d_out);
    } else {
        gemm_bt<2, true><<<dim3(32, 251), blk, 0, stream>>>(X1, W2vT, b2v, d_out, NNODES, VDIM, 2048, VDIM);
        logsoftmax_rows<<<dim3(NNODES), blk, 0, stream>>>((float*)d_out, VDIM);
    }
}